// Round 3
// baseline (549.033 us; speedup 1.0000x reference)
//
#include <hip/hip_runtime.h>

using u16 = unsigned short;
using f16 = _Float16;
typedef __attribute__((ext_vector_type(8))) _Float16 f16x8;
typedef __attribute__((ext_vector_type(4))) _Float16 f16x4;
typedef __attribute__((ext_vector_type(4))) float f32x4;

#define DEV static __device__ __forceinline__

// async global->LDS, 16B per lane. LDS dest must be wave-uniform base + lane*16.
DEV void gload16(const void* g, const void* l) {
    __builtin_amdgcn_global_load_lds((const __attribute__((address_space(1))) void*)g,
                                     (__attribute__((address_space(3))) void*)l,
                                     16, 0, 0);
}

DEV f32x4 mfma16(f16x8 a, f16x8 b, f32x4 c) {
    return __builtin_amdgcn_mfma_f32_16x16x32_f16(a, b, c, 0, 0, 0);
}

// XOR-swizzle involution: staging wrote global chunk (cs ^ (row&7)) at slot cs,
// so global chunk q sits at slot q^(row&7). Returns ELEMENT offset.
DEV int swz(int row, int chunk) { return (chunk ^ (row & 7)) * 8; }

__global__ __launch_bounds__(256) void cvt_f32_f16(const float* __restrict__ src,
                                                   f16* __restrict__ dst, int n4) {
    int i = blockIdx.x * 256 + threadIdx.x;
    if (i >= n4) return;
    f32x4 v = *((const f32x4*)src + i);
    f16x4 o;
    o[0] = (f16)v[0]; o[1] = (f16)v[1]; o[2] = (f16)v[2]; o[3] = (f16)v[3];
    *((f16x4*)dst + i) = o;
}

// C[m][n] = sum_k A[m][k] * Bw[n][k];  A:(M,K) f16, Bw:(N,K) f16. 128x128 tile, BK=64.
template <bool F32OUT>
__global__ __launch_bounds__(256) void gemm_bt(const f16* __restrict__ A,
                                               const f16* __restrict__ Bw,
                                               void* __restrict__ Cout,
                                               int M, int N, int K) {
    __shared__ alignas(16) f16 As[128 * 64];
    __shared__ alignas(16) f16 Bs[128 * 64];
    const int tid = threadIdx.x;
    const int lane = tid & 63, w = tid >> 6;
    const int l15 = lane & 15, lg = lane >> 4;
    const int m0 = blockIdx.x * 128, n0 = blockIdx.y * 128;
    const int wr = (w >> 1) * 64, wc = (w & 1) * 64;
    f32x4 acc[4][4] = {};
    const int nk = K >> 6;

    auto stage = [&](int k0) {
#pragma unroll
        for (int it = 0; it < 4; ++it) {
            int idx = it * 256 + tid;
            int row = idx >> 3, cs = idx & 7;
            int gc = (cs ^ (row & 7)) * 8;
            gload16(A + (size_t)(m0 + row) * K + k0 + gc, (const char*)As + idx * 16);
            gload16(Bw + (size_t)(n0 + row) * K + k0 + gc, (const char*)Bs + idx * 16);
        }
    };
    stage(0);
    for (int kt = 0; kt < nk; ++kt) {
        __syncthreads();
#pragma unroll
        for (int kk = 0; kk < 2; ++kk) {
            f16x8 af[4], bfr[4];
#pragma unroll
            for (int i = 0; i < 4; ++i) {
                int ar = wr + i * 16 + l15;
                af[i] = *(const f16x8*)&As[ar * 64 + swz(ar, kk * 4 + lg)];
                int br = wc + i * 16 + l15;
                bfr[i] = *(const f16x8*)&Bs[br * 64 + swz(br, kk * 4 + lg)];
            }
#pragma unroll
            for (int i = 0; i < 4; ++i)
#pragma unroll
                for (int j = 0; j < 4; ++j)
                    acc[i][j] = mfma16(af[i], bfr[j], acc[i][j]);
        }
        __syncthreads();
        if (kt + 1 < nk) stage((kt + 1) << 6);
    }
#pragma unroll
    for (int i = 0; i < 4; ++i)
#pragma unroll
        for (int j = 0; j < 4; ++j)
#pragma unroll
            for (int r = 0; r < 4; ++r) {
                size_t rr = (size_t)(m0 + wr + i * 16 + lg * 4 + r);
                int cc = n0 + wc + j * 16 + l15;
                if constexpr (F32OUT) ((float*)Cout)[rr * (size_t)N + cc] = acc[i][j][r];
                else                  ((f16*)Cout)[rr * (size_t)N + cc]   = (f16)acc[i][j][r];
            }
}

// Fused RMSNorm + RoPE, f32 internal math; emits SPLIT fp16: hi + lo*32.
// One wave per 256-wide head vector; RoPE partner via shfl_xor(32).
__global__ __launch_bounds__(256) void norm_rope_split(const f16* __restrict__ in, int inStride, int inColOff,
                                                       f16* __restrict__ outH, f16* __restrict__ outL, int outStride,
                                                       const float* __restrict__ scale,
                                                       const float* __restrict__ cosT,
                                                       const float* __restrict__ sinT,
                                                       int hBits, float outScale, int nvec) {
    int vec = blockIdx.x * 4 + (threadIdx.x >> 6);
    if (vec >= nvec) return;
    const int lane = threadIdx.x & 63;
    const int row = vec >> hBits;
    const int h = vec & ((1 << hBits) - 1);
    const int s = row & 4095;
    const f16* p = in + (size_t)row * inStride + inColOff + h * 256 + lane * 4;
    f16x4 raw = *(const f16x4*)p;
    float f[4];
    float ss = 0.f;
#pragma unroll
    for (int i = 0; i < 4; ++i) { f[i] = (float)raw[i]; ss += f[i] * f[i]; }
#pragma unroll
    for (int off = 1; off < 64; off <<= 1) ss += __shfl_xor(ss, off, 64);
    const float inv = rsqrtf(ss * (1.0f / 256.0f) + 1e-6f);
    f32x4 sc4 = *(const f32x4*)(scale + lane * 4);
    float xn[4];
#pragma unroll
    for (int i = 0; i < 4; ++i) xn[i] = f[i] * inv * (1.0f + sc4[i]);
    f32x4 c4 = *(const f32x4*)(cosT + (size_t)s * 256 + lane * 4);
    f32x4 s4 = *(const f32x4*)(sinT + (size_t)s * 256 + lane * 4);
    f16x4 oh, ol;
#pragma unroll
    for (int i = 0; i < 4; ++i) {
        float pv = __shfl_xor(xn[i], 32, 64);
        float rot = (lane < 32) ? -pv : pv;
        float val = (xn[i] * c4[i] + rot * s4[i]) * outScale;
        f16 hi = (f16)val;
        oh[i] = hi;
        ol[i] = (f16)((val - (float)hi) * 32.0f);  // lo scaled x32: stays fp16-normal
    }
    size_t ob = (size_t)row * outStride + h * 256 + lane * 4;
    *(f16x4*)(outH + ob) = oh;
    *(f16x4*)(outL + ob) = ol;
}

// V slice of qkv (cols 1280..1535) -> vt[b][d][s]  (b:2, d:256, s:4096). Pure bit-moves.
__global__ __launch_bounds__(256) void transpose_v(const u16* __restrict__ qkv, u16* __restrict__ vt) {
    __shared__ u16 t[64][72];
    const int s0 = blockIdx.x * 64, d0 = blockIdx.y * 64, b = blockIdx.z;
#pragma unroll
    for (int i = 0; i < 16; ++i) {
        int idx = threadIdx.x + i * 256;
        int si = idx >> 6, di = idx & 63;
        t[si][di] = qkv[(size_t)(b * 4096 + s0 + si) * 1536 + 1280 + d0 + di];
    }
    __syncthreads();
#pragma unroll
    for (int i = 0; i < 16; ++i) {
        int idx = threadIdx.x + i * 256;
        int dj = idx >> 6, sj = idx & 63;
        vt[(size_t)b * (256 * 4096) + (size_t)(d0 + dj) * 4096 + (s0 + sj)] = t[sj][dj];
    }
}

// Causal flash attention, split-precision QK^T (q,k = hi + lo/32), P staged x64.
// Grid: (64 q-tiles reversed, H=4, B=2). 4 waves, QT=KT=64, HD=256.
__global__ __launch_bounds__(256) void attn(const f16* __restrict__ qhg, const f16* __restrict__ qlg,
                                            const f16* __restrict__ khg, const f16* __restrict__ klg,
                                            const f16* __restrict__ vtg,
                                            f16* __restrict__ ctx) {
    __shared__ alignas(16) f16 Kh[64 * 256];   // [kv][d] hi, XOR-swizzled chunks
    __shared__ alignas(16) f16 Kl[64 * 256];   // [kv][d] lo*32
    __shared__ alignas(16) f16 Vs[256 * 64];   // [d][kv]
    __shared__ alignas(16) f16 Ps[4][16 * 64]; // per-wave P*64, swizzled
    const int tid = threadIdx.x;
    const int lane = tid & 63, w = tid >> 6;
    const int l15 = lane & 15, lg = lane >> 4;
    const int qt = 63 - (int)blockIdx.x;       // heavy blocks dispatch first
    const int h = blockIdx.y, b = blockIdx.z;

    // Q fragments (hi+lo) in registers: 16 rows x 256 d per wave
    f16x8 qfh[8], qfl[8];
    {
        const size_t qoff = (size_t)(b * 4096 + qt * 64 + w * 16 + l15) * 1024 + h * 256 + lg * 8;
#pragma unroll
        for (int e = 0; e < 8; ++e) {
            qfh[e] = *(const f16x8*)(qhg + qoff + e * 32);
            qfl[e] = *(const f16x8*)(qlg + qoff + e * 32);
        }
    }
    f32x4 ao[16] = {};
    float m_[4] = {-3e38f, -3e38f, -3e38f, -3e38f};
    float l_[4] = {0.f, 0.f, 0.f, 0.f};
    const int nt = qt + 1;

    auto stageKV = [&](int t) {
#pragma unroll
        for (int it = 0; it < 8; ++it) {
            int idx = it * 256 + tid;
            {
                int r = idx >> 5, cs = idx & 31;
                int gc = (cs ^ (r & 7)) * 8;
                size_t src = (size_t)(b * 4096 + t * 64 + r) * 256 + gc;
                gload16(khg + src, (const char*)Kh + idx * 16);
                gload16(klg + src, (const char*)Kl + idx * 16);
            }
            {
                int r = idx >> 3, cs = idx & 7;
                int gc = (cs ^ (r & 7)) * 8;
                gload16(vtg + (size_t)b * (256 * 4096) + (size_t)r * 4096 + t * 64 + gc,
                        (const char*)Vs + idx * 16);
            }
        }
    };
    stageKV(0);
    for (int t = 0; t < nt; ++t) {
        __syncthreads();  // staging complete (compiler drains vmcnt before s_barrier)
        // ---- QK^T split: sc = qh*kh; s2 = qh*kl + ql*kh (both x32); total = sc + s2/32
        f32x4 sc[4] = {}, s2[4] = {};
#pragma unroll
        for (int c = 0; c < 4; ++c) {
            int krow = c * 16 + l15;
#pragma unroll
            for (int kk = 0; kk < 8; ++kk) {
                int o = krow * 256 + swz(krow, kk * 4 + lg);
                f16x8 kbh = *(const f16x8*)&Kh[o];
                f16x8 kbl = *(const f16x8*)&Kl[o];
                sc[c] = mfma16(qfh[kk], kbh, sc[c]);
                s2[c] = mfma16(qfh[kk], kbl, s2[c]);
                s2[c] = mfma16(qfl[kk], kbh, s2[c]);
            }
        }
#pragma unroll
        for (int c = 0; c < 4; ++c)
#pragma unroll
            for (int r = 0; r < 4; ++r)
                sc[c][r] = sc[c][r] + s2[c][r] * (1.0f / 32.0f);
        // ---- causal mask (diagonal tile only)
        if (t == qt) {
#pragma unroll
            for (int c = 0; c < 4; ++c)
#pragma unroll
                for (int r = 0; r < 4; ++r) {
                    int qi = w * 16 + lg * 4 + r;
                    int ki = c * 16 + l15;
                    if (ki > qi) sc[c][r] = -3e38f;
                }
        }
        // ---- online softmax (per 4 rows owned by this lane-group)
#pragma unroll
        for (int r = 0; r < 4; ++r) {
            float v = fmaxf(fmaxf(sc[0][r], sc[1][r]), fmaxf(sc[2][r], sc[3][r]));
            v = fmaxf(v, __shfl_xor(v, 1, 64));
            v = fmaxf(v, __shfl_xor(v, 2, 64));
            v = fmaxf(v, __shfl_xor(v, 4, 64));
            v = fmaxf(v, __shfl_xor(v, 8, 64));
            const float mn = fmaxf(m_[r], v);
            const float resc = __builtin_amdgcn_exp2f((m_[r] - mn) * 1.44269504f);
            m_[r] = mn;
            float rs = 0.f;
#pragma unroll
            for (int c = 0; c < 4; ++c) {
                float pp = __builtin_amdgcn_exp2f((sc[c][r] - mn) * 1.44269504f);
                sc[c][r] = pp;
                rs += pp;
            }
            rs += __shfl_xor(rs, 1, 64); rs += __shfl_xor(rs, 2, 64);
            rs += __shfl_xor(rs, 4, 64); rs += __shfl_xor(rs, 8, 64);
            l_[r] = l_[r] * resc + rs;
#pragma unroll
            for (int df = 0; df < 16; ++df) ao[df][r] *= resc;
        }
        // ---- P*64 -> LDS (swizzled; x64 keeps small P out of fp16 subnormal range)
#pragma unroll
        for (int c = 0; c < 4; ++c)
#pragma unroll
            for (int r = 0; r < 4; ++r) {
                int prow = lg * 4 + r;
                int chunk = c * 2 + (l15 >> 3);
                Ps[w][prow * 64 + ((chunk ^ (prow & 7)) * 8) + (l15 & 7)] = (f16)(sc[c][r] * 64.0f);
            }
        __syncthreads();
#pragma unroll
        for (int kk = 0; kk < 2; ++kk) {
            f16x8 pa = *(const f16x8*)&Ps[w][l15 * 64 + swz(l15, kk * 4 + lg)];
#pragma unroll
            for (int df = 0; df < 16; ++df) {
                int vrow = df * 16 + l15;
                f16x8 vb = *(const f16x8*)&Vs[vrow * 64 + swz(vrow, kk * 4 + lg)];
                ao[df] = mfma16(pa, vb, ao[df]);
            }
        }
        __syncthreads();  // all LDS reads done before restaging
        if (t + 1 < nt) stageKV(t + 1);
    }
    // ---- epilogue: ctx = ao / (64 * l)   (undo the P x64)
    float rl[4];
#pragma unroll
    for (int r = 0; r < 4; ++r) rl[r] = 1.0f / (l_[r] * 64.0f);
    const size_t orow0 = (size_t)(b * 4096 + qt * 64 + w * 16);
#pragma unroll
    for (int df = 0; df < 16; ++df)
#pragma unroll
        for (int r = 0; r < 4; ++r)
            ctx[(orow0 + lg * 4 + r) * 1024 + h * 256 + df * 16 + l15] = (f16)(ao[df][r] * rl[r]);
}

extern "C" void kernel_launch(void* const* d_in, const int* in_sizes, int n_in,
                              void* d_out, int out_size, void* d_ws, size_t ws_size,
                              hipStream_t stream) {
    (void)in_sizes; (void)n_in; (void)out_size; (void)ws_size;
    const float* x    = (const float*)d_in[0];
    const float* Wq   = (const float*)d_in[1];
    const float* Wk   = (const float*)d_in[2];
    const float* Wv   = (const float*)d_in[3];
    const float* Wo   = (const float*)d_in[4];
    const float* qsc  = (const float*)d_in[5];
    const float* ksc  = (const float*)d_in[6];
    const float* cosT = (const float*)d_in[7];
    const float* sinT = (const float*)d_in[8];
    // d_in[9] = mask: causal triu(k=1), structure known -> not read.

    // workspace layout (f16 elements), total ~102 MiB
    f16* xb   = (f16*)d_ws;                      // 8192*640
    f16* wcat = xb + (size_t)8192 * 640;         // 1536*640  (Wq | Wk | Wv rows)
    f16* wob  = wcat + (size_t)1536 * 640;       // 640*1024
    f16* qkv  = wob + (size_t)640 * 1024;        // 8192*1536 (q | k | v)
    f16* qh   = qkv + (size_t)8192 * 1536;       // 8192*1024
    f16* ql   = qh + (size_t)8192 * 1024;        // 8192*1024
    f16* kh   = ql + (size_t)8192 * 1024;        // 8192*256
    f16* kl   = kh + (size_t)8192 * 256;         // 8192*256
    f16* vt   = kl + (size_t)8192 * 256;         // 2*256*4096
    f16* ctxb = vt + (size_t)2 * 256 * 4096;     // 8192*1024

    // f32 -> f16 converts
    cvt_f32_f16<<<5120, 256, 0, stream>>>(x, xb, 1310720);
    cvt_f32_f16<<<640, 256, 0, stream>>>(Wq, wcat, 163840);
    cvt_f32_f16<<<160, 256, 0, stream>>>(Wk, wcat + 655360, 40960);
    cvt_f32_f16<<<160, 256, 0, stream>>>(Wv, wcat + 819200, 40960);
    cvt_f32_f16<<<640, 256, 0, stream>>>(Wo, wob, 163840);

    // fused QKV projection: (8192,640) x (1536,640)^T -> (8192,1536) f16
    gemm_bt<false><<<dim3(64, 12), 256, 0, stream>>>(xb, wcat, qkv, 8192, 1536, 640);

    // RMSNorm + RoPE, split hi/lo outputs; q gets the 1/16 scaling folded in
    norm_rope_split<<<8192, 256, 0, stream>>>(qkv, 1536, 0,    qh, ql, 1024, qsc, cosT, sinT, 2, 0.0625f, 32768);
    norm_rope_split<<<2048, 256, 0, stream>>>(qkv, 1536, 1024, kh, kl, 256,  ksc, cosT, sinT, 0, 1.0f,    8192);

    // V -> V^T for conflict-free PV B-fragments
    transpose_v<<<dim3(64, 4, 2), 256, 0, stream>>>((const u16*)qkv, (u16*)vt);

    // causal flash attention (split-precision scores)
    attn<<<dim3(64, 4, 2), 256, 0, stream>>>(qh, ql, kh, kl, vt, ctxb);

    // output projection: (8192,1024) x (640,1024)^T -> (8192,640) f32
    gemm_bt<true><<<dim3(64, 5), 256, 0, stream>>>(ctxb, wob, d_out, 8192, 640, 1024);
}

// Round 4
// 548.979 us; speedup vs baseline: 1.0001x; 1.0001x over previous
//
#include <hip/hip_runtime.h>

using u16 = unsigned short;
using f16 = _Float16;
typedef __attribute__((ext_vector_type(8))) _Float16 f16x8;
typedef __attribute__((ext_vector_type(4))) _Float16 f16x4;
typedef __attribute__((ext_vector_type(4))) float f32x4;

#define DEV static __device__ __forceinline__

// async global->LDS, 16B per lane. LDS dest must be wave-uniform base + lane*16.
DEV void gload16(const void* g, const void* l) {
    __builtin_amdgcn_global_load_lds((const __attribute__((address_space(1))) void*)g,
                                     (__attribute__((address_space(3))) void*)l,
                                     16, 0, 0);
}

DEV f32x4 mfma16(f16x8 a, f16x8 b, f32x4 c) {
    return __builtin_amdgcn_mfma_f32_16x16x32_f16(a, b, c, 0, 0, 0);
}

// XOR-swizzle involution: staging wrote global chunk (cs ^ (row&7)) at slot cs,
// so global chunk q sits at slot q^(row&7). Returns ELEMENT offset.
DEV int swz(int row, int chunk) { return (chunk ^ (row & 7)) * 8; }

__global__ __launch_bounds__(256) void cvt_f32_f16(const float* __restrict__ src,
                                                   f16* __restrict__ dst, int n4) {
    int i = blockIdx.x * 256 + threadIdx.x;
    if (i >= n4) return;
    f32x4 v = *((const f32x4*)src + i);
    f16x4 o;
    o[0] = (f16)v[0]; o[1] = (f16)v[1]; o[2] = (f16)v[2]; o[3] = (f16)v[3];
    *((f16x4*)dst + i) = o;
}

// C[m][n] = sum_k A[m][k] * Bw[n][k];  A:(M,K) f16, Bw:(N,K) f16. 128x128 tile, BK=64.
template <bool F32OUT>
__global__ __launch_bounds__(256) void gemm_bt(const f16* __restrict__ A,
                                               const f16* __restrict__ Bw,
                                               void* __restrict__ Cout,
                                               int M, int N, int K) {
    __shared__ alignas(16) f16 As[128 * 64];
    __shared__ alignas(16) f16 Bs[128 * 64];
    const int tid = threadIdx.x;
    const int lane = tid & 63, w = tid >> 6;
    const int l15 = lane & 15, lg = lane >> 4;
    const int m0 = blockIdx.x * 128, n0 = blockIdx.y * 128;
    const int wr = (w >> 1) * 64, wc = (w & 1) * 64;
    f32x4 acc[4][4] = {};
    const int nk = K >> 6;

    auto stage = [&](int k0) {
#pragma unroll
        for (int it = 0; it < 4; ++it) {
            int idx = it * 256 + tid;
            int row = idx >> 3, cs = idx & 7;
            int gc = (cs ^ (row & 7)) * 8;
            gload16(A + (size_t)(m0 + row) * K + k0 + gc, (const char*)As + idx * 16);
            gload16(Bw + (size_t)(n0 + row) * K + k0 + gc, (const char*)Bs + idx * 16);
        }
    };
    stage(0);
    for (int kt = 0; kt < nk; ++kt) {
        __syncthreads();
#pragma unroll
        for (int kk = 0; kk < 2; ++kk) {
            f16x8 af[4], bfr[4];
#pragma unroll
            for (int i = 0; i < 4; ++i) {
                int ar = wr + i * 16 + l15;
                af[i] = *(const f16x8*)&As[ar * 64 + swz(ar, kk * 4 + lg)];
                int br = wc + i * 16 + l15;
                bfr[i] = *(const f16x8*)&Bs[br * 64 + swz(br, kk * 4 + lg)];
            }
#pragma unroll
            for (int i = 0; i < 4; ++i)
#pragma unroll
                for (int j = 0; j < 4; ++j)
                    acc[i][j] = mfma16(af[i], bfr[j], acc[i][j]);
        }
        __syncthreads();
        if (kt + 1 < nk) stage((kt + 1) << 6);
    }
#pragma unroll
    for (int i = 0; i < 4; ++i)
#pragma unroll
        for (int j = 0; j < 4; ++j)
#pragma unroll
            for (int r = 0; r < 4; ++r) {
                size_t rr = (size_t)(m0 + wr + i * 16 + lg * 4 + r);
                int cc = n0 + wc + j * 16 + l15;
                if constexpr (F32OUT) ((float*)Cout)[rr * (size_t)N + cc] = acc[i][j][r];
                else                  ((f16*)Cout)[rr * (size_t)N + cc]   = (f16)acc[i][j][r];
            }
}

// Fused RMSNorm + RoPE, f32 internal math; emits SPLIT fp16: hi + lo*32.
// One wave per 256-wide head vector; RoPE partner via shfl_xor(32).
__global__ __launch_bounds__(256) void norm_rope_split(const f16* __restrict__ in, int inStride, int inColOff,
                                                       f16* __restrict__ outH, f16* __restrict__ outL, int outStride,
                                                       const float* __restrict__ scale,
                                                       const float* __restrict__ cosT,
                                                       const float* __restrict__ sinT,
                                                       int hBits, float outScale, int nvec) {
    int vec = blockIdx.x * 4 + (threadIdx.x >> 6);
    if (vec >= nvec) return;
    const int lane = threadIdx.x & 63;
    const int row = vec >> hBits;
    const int h = vec & ((1 << hBits) - 1);
    const int s = row & 4095;
    const f16* p = in + (size_t)row * inStride + inColOff + h * 256 + lane * 4;
    f16x4 raw = *(const f16x4*)p;
    float f[4];
    float ss = 0.f;
#pragma unroll
    for (int i = 0; i < 4; ++i) { f[i] = (float)raw[i]; ss += f[i] * f[i]; }
#pragma unroll
    for (int off = 1; off < 64; off <<= 1) ss += __shfl_xor(ss, off, 64);
    const float inv = rsqrtf(ss * (1.0f / 256.0f) + 1e-6f);
    f32x4 sc4 = *(const f32x4*)(scale + lane * 4);
    float xn[4];
#pragma unroll
    for (int i = 0; i < 4; ++i) xn[i] = f[i] * inv * (1.0f + sc4[i]);
    f32x4 c4 = *(const f32x4*)(cosT + (size_t)s * 256 + lane * 4);
    f32x4 s4 = *(const f32x4*)(sinT + (size_t)s * 256 + lane * 4);
    f16x4 oh, ol;
#pragma unroll
    for (int i = 0; i < 4; ++i) {
        float pv = __shfl_xor(xn[i], 32, 64);
        float rot = (lane < 32) ? -pv : pv;
        float val = (xn[i] * c4[i] + rot * s4[i]) * outScale;
        f16 hi = (f16)val;
        oh[i] = hi;
        ol[i] = (f16)((val - (float)hi) * 32.0f);  // lo scaled x32: stays fp16-normal
    }
    size_t ob = (size_t)row * outStride + h * 256 + lane * 4;
    *(f16x4*)(outH + ob) = oh;
    *(f16x4*)(outL + ob) = ol;
}

// V slice of qkv (cols 1280..1535) -> vt[b][d][s]  (b:2, d:256, s:4096). Pure bit-moves.
__global__ __launch_bounds__(256) void transpose_v(const u16* __restrict__ qkv, u16* __restrict__ vt) {
    __shared__ u16 t[64][72];
    const int s0 = blockIdx.x * 64, d0 = blockIdx.y * 64, b = blockIdx.z;
#pragma unroll
    for (int i = 0; i < 16; ++i) {
        int idx = threadIdx.x + i * 256;
        int si = idx >> 6, di = idx & 63;
        t[si][di] = qkv[(size_t)(b * 4096 + s0 + si) * 1536 + 1280 + d0 + di];
    }
    __syncthreads();
#pragma unroll
    for (int i = 0; i < 16; ++i) {
        int idx = threadIdx.x + i * 256;
        int dj = idx >> 6, sj = idx & 63;
        vt[(size_t)b * (256 * 4096) + (size_t)(d0 + dj) * 4096 + (s0 + sj)] = t[sj][dj];
    }
}

// Causal flash attention, split-precision QK^T (q,k = hi + lo/32), P staged x64.
// Grid: (64 q-tiles reversed, H=4, B=2). 4 waves, QT=KT=64, HD=256.
__global__ __launch_bounds__(256) void attn(const f16* __restrict__ qhg, const f16* __restrict__ qlg,
                                            const f16* __restrict__ khg, const f16* __restrict__ klg,
                                            const f16* __restrict__ vtg,
                                            f16* __restrict__ ctx) {
    __shared__ alignas(16) f16 Kh[64 * 256];   // [kv][d] hi, XOR-swizzled chunks
    __shared__ alignas(16) f16 Kl[64 * 256];   // [kv][d] lo*32
    __shared__ alignas(16) f16 Vs[256 * 64];   // [d][kv]
    __shared__ alignas(16) f16 Ps[4][16 * 64]; // per-wave P*64, swizzled
    const int tid = threadIdx.x;
    const int lane = tid & 63, w = tid >> 6;
    const int l15 = lane & 15, lg = lane >> 4;
    const int qt = 63 - (int)blockIdx.x;       // heavy blocks dispatch first
    const int h = blockIdx.y, b = blockIdx.z;

    // Q fragments (hi+lo) in registers: 16 rows x 256 d per wave
    f16x8 qfh[8], qfl[8];
    {
        const size_t qoff = (size_t)(b * 4096 + qt * 64 + w * 16 + l15) * 1024 + h * 256 + lg * 8;
#pragma unroll
        for (int e = 0; e < 8; ++e) {
            qfh[e] = *(const f16x8*)(qhg + qoff + e * 32);
            qfl[e] = *(const f16x8*)(qlg + qoff + e * 32);
        }
    }
    f32x4 ao[16] = {};
    float m_[4] = {-3e38f, -3e38f, -3e38f, -3e38f};
    float l_[4] = {0.f, 0.f, 0.f, 0.f};
    const int nt = qt + 1;

    auto stageKV = [&](int t) {
#pragma unroll
        for (int it = 0; it < 8; ++it) {
            int idx = it * 256 + tid;
            {
                int r = idx >> 5, cs = idx & 31;
                int gc = (cs ^ (r & 7)) * 8;
                size_t src = (size_t)(b * 4096 + t * 64 + r) * 256 + gc;
                gload16(khg + src, (const char*)Kh + idx * 16);
                gload16(klg + src, (const char*)Kl + idx * 16);
            }
            {
                int r = idx >> 3, cs = idx & 7;
                int gc = (cs ^ (r & 7)) * 8;
                gload16(vtg + (size_t)b * (256 * 4096) + (size_t)r * 4096 + t * 64 + gc,
                        (const char*)Vs + idx * 16);
            }
        }
    };
    stageKV(0);
    for (int t = 0; t < nt; ++t) {
        __syncthreads();  // staging complete (compiler drains vmcnt before s_barrier)
        // ---- QK^T split: sc = qh*kh; s2 = qh*kl + ql*kh (both x32); total = sc + s2/32
        f32x4 sc[4] = {}, s2[4] = {};
#pragma unroll
        for (int c = 0; c < 4; ++c) {
            int krow = c * 16 + l15;
#pragma unroll
            for (int kk = 0; kk < 8; ++kk) {
                int o = krow * 256 + swz(krow, kk * 4 + lg);
                f16x8 kbh = *(const f16x8*)&Kh[o];
                f16x8 kbl = *(const f16x8*)&Kl[o];
                sc[c] = mfma16(qfh[kk], kbh, sc[c]);
                s2[c] = mfma16(qfh[kk], kbl, s2[c]);
                s2[c] = mfma16(qfl[kk], kbh, s2[c]);
            }
        }
#pragma unroll
        for (int c = 0; c < 4; ++c)
#pragma unroll
            for (int r = 0; r < 4; ++r)
                sc[c][r] = sc[c][r] + s2[c][r] * (1.0f / 32.0f);
        // ---- causal mask (diagonal tile only)
        if (t == qt) {
#pragma unroll
            for (int c = 0; c < 4; ++c)
#pragma unroll
                for (int r = 0; r < 4; ++r) {
                    int qi = w * 16 + lg * 4 + r;
                    int ki = c * 16 + l15;
                    if (ki > qi) sc[c][r] = -3e38f;
                }
        }
        // ---- online softmax (per 4 rows owned by this lane-group)
#pragma unroll
        for (int r = 0; r < 4; ++r) {
            float v = fmaxf(fmaxf(sc[0][r], sc[1][r]), fmaxf(sc[2][r], sc[3][r]));
            v = fmaxf(v, __shfl_xor(v, 1, 64));
            v = fmaxf(v, __shfl_xor(v, 2, 64));
            v = fmaxf(v, __shfl_xor(v, 4, 64));
            v = fmaxf(v, __shfl_xor(v, 8, 64));
            const float mn = fmaxf(m_[r], v);
            const float resc = __builtin_amdgcn_exp2f((m_[r] - mn) * 1.44269504f);
            m_[r] = mn;
            float rs = 0.f;
#pragma unroll
            for (int c = 0; c < 4; ++c) {
                float pp = __builtin_amdgcn_exp2f((sc[c][r] - mn) * 1.44269504f);
                sc[c][r] = pp;
                rs += pp;
            }
            rs += __shfl_xor(rs, 1, 64); rs += __shfl_xor(rs, 2, 64);
            rs += __shfl_xor(rs, 4, 64); rs += __shfl_xor(rs, 8, 64);
            l_[r] = l_[r] * resc + rs;
#pragma unroll
            for (int df = 0; df < 16; ++df) ao[df][r] *= resc;
        }
        // ---- P*64 -> LDS (swizzled; x64 keeps small P out of fp16 subnormal range)
#pragma unroll
        for (int c = 0; c < 4; ++c)
#pragma unroll
            for (int r = 0; r < 4; ++r) {
                int prow = lg * 4 + r;
                int chunk = c * 2 + (l15 >> 3);
                Ps[w][prow * 64 + ((chunk ^ (prow & 7)) * 8) + (l15 & 7)] = (f16)(sc[c][r] * 64.0f);
            }
        __syncthreads();
#pragma unroll
        for (int kk = 0; kk < 2; ++kk) {
            f16x8 pa = *(const f16x8*)&Ps[w][l15 * 64 + swz(l15, kk * 4 + lg)];
#pragma unroll
            for (int df = 0; df < 16; ++df) {
                int vrow = df * 16 + l15;
                f16x8 vb = *(const f16x8*)&Vs[vrow * 64 + swz(vrow, kk * 4 + lg)];
                ao[df] = mfma16(pa, vb, ao[df]);
            }
        }
        __syncthreads();  // all LDS reads done before restaging
        if (t + 1 < nt) stageKV(t + 1);
    }
    // ---- epilogue: ctx = ao / (64 * l)   (undo the P x64)
    float rl[4];
#pragma unroll
    for (int r = 0; r < 4; ++r) rl[r] = 1.0f / (l_[r] * 64.0f);
    const size_t orow0 = (size_t)(b * 4096 + qt * 64 + w * 16);
#pragma unroll
    for (int df = 0; df < 16; ++df)
#pragma unroll
        for (int r = 0; r < 4; ++r)
            ctx[(orow0 + lg * 4 + r) * 1024 + h * 256 + df * 16 + l15] = (f16)(ao[df][r] * rl[r]);
}

extern "C" void kernel_launch(void* const* d_in, const int* in_sizes, int n_in,
                              void* d_out, int out_size, void* d_ws, size_t ws_size,
                              hipStream_t stream) {
    (void)in_sizes; (void)n_in; (void)out_size; (void)ws_size;
    const float* x    = (const float*)d_in[0];
    const float* Wq   = (const float*)d_in[1];
    const float* Wk   = (const float*)d_in[2];
    const float* Wv   = (const float*)d_in[3];
    const float* Wo   = (const float*)d_in[4];
    const float* qsc  = (const float*)d_in[5];
    const float* ksc  = (const float*)d_in[6];
    const float* cosT = (const float*)d_in[7];
    const float* sinT = (const float*)d_in[8];
    // d_in[9] = mask: causal triu(k=1), structure known -> not read.

    // workspace layout (f16 elements), total ~102 MiB
    f16* xb   = (f16*)d_ws;                      // 8192*640
    f16* wcat = xb + (size_t)8192 * 640;         // 1536*640  (Wq | Wk | Wv rows)
    f16* wob  = wcat + (size_t)1536 * 640;       // 640*1024
    f16* qkv  = wob + (size_t)640 * 1024;        // 8192*1536 (q | k | v)
    f16* qh   = qkv + (size_t)8192 * 1536;       // 8192*1024
    f16* ql   = qh + (size_t)8192 * 1024;        // 8192*1024
    f16* kh   = ql + (size_t)8192 * 1024;        // 8192*256
    f16* kl   = kh + (size_t)8192 * 256;         // 8192*256
    f16* vt   = kl + (size_t)8192 * 256;         // 2*256*4096
    f16* ctxb = vt + (size_t)2 * 256 * 4096;     // 8192*1024

    // f32 -> f16 converts
    cvt_f32_f16<<<5120, 256, 0, stream>>>(x, xb, 1310720);
    cvt_f32_f16<<<640, 256, 0, stream>>>(Wq, wcat, 163840);
    cvt_f32_f16<<<160, 256, 0, stream>>>(Wk, wcat + 655360, 40960);
    cvt_f32_f16<<<160, 256, 0, stream>>>(Wv, wcat + 819200, 40960);
    cvt_f32_f16<<<640, 256, 0, stream>>>(Wo, wob, 163840);

    // fused QKV projection: (8192,640) x (1536,640)^T -> (8192,1536) f16
    gemm_bt<false><<<dim3(64, 12), 256, 0, stream>>>(xb, wcat, qkv, 8192, 1536, 640);

    // RMSNorm + RoPE, split hi/lo outputs; q gets the 1/16 scaling folded in
    norm_rope_split<<<8192, 256, 0, stream>>>(qkv, 1536, 0,    qh, ql, 1024, qsc, cosT, sinT, 2, 0.0625f, 32768);
    norm_rope_split<<<2048, 256, 0, stream>>>(qkv, 1536, 1024, kh, kl, 256,  ksc, cosT, sinT, 0, 1.0f,    8192);

    // V -> V^T for conflict-free PV B-fragments
    transpose_v<<<dim3(64, 4, 2), 256, 0, stream>>>((const u16*)qkv, (u16*)vt);

    // causal flash attention (split-precision scores)
    attn<<<dim3(64, 4, 2), 256, 0, stream>>>(qh, ql, kh, kl, vt, ctxb);

    // output projection: (8192,1024) x (640,1024)^T -> (8192,640) f32
    gemm_bt<true><<<dim3(64, 5), 256, 0, stream>>>(ctxb, wob, d_out, 8192, 640, 1024);
}